// Round 4
// baseline (148.786 us; speedup 1.0000x reference)
//
#include <hip/hip_runtime.h>
#include <hip/hip_bf16.h>

// Problem: CrossViewFusionModule
//   global_query: [B=16, D=256] f32
//   value:        [B=16, D=256, W=128, H=128] f32
//   q = l2norm(q, axis=-1); v = l2norm(value, axis=D)
//   score[b,wh] = sum_d q[b,d]*v[b,d,wh]
//   attn = (score - min_b) / (max_b - min_b + 1e-8)   (min/max over wh per b)
//   context = attn * v
//   outputs: (context [B,D,W,H], attn [B,1,W,H]) concatenated in d_out.
//
// R4: score pass was latency-bound (1 wave/SIMD, ~0.5 KB in flight/CU).
// Now: 1024-thread blocks, 4 d-quarter groups x 256 wh-lanes, LDS combine
// (no extra HBM traffic), unroll 16 -> ~4 KB in flight/CU. ctx keeps R3's
// nt-store + L3-mirror scheme (ctx was already near its write floor).

#define B_  16
#define D_  256
#define WH_ 16384   // 128*128

// ---- monotone float <-> sortable uint mapping (for exact atomic min/max) ----
__device__ __forceinline__ unsigned int fmap(float f) {
    unsigned int u = __float_as_uint(f);
    return (u & 0x80000000u) ? ~u : (u | 0x80000000u);
}
__device__ __forceinline__ float funmap(unsigned int u) {
    unsigned int b = (u & 0x80000000u) ? (u ^ 0x80000000u) : ~u;
    return __uint_as_float(b);
}

typedef float f32x4_t __attribute__((ext_vector_type(4)));
__device__ __forceinline__ void nt_store4(float* p, float4 v) {
    f32x4_t w = {v.x, v.y, v.z, v.w};
    __builtin_nontemporal_store(w, (f32x4_t*)p);   // global_store_dwordx4 ... nt
}

__global__ void init_mm_kernel(unsigned int* __restrict__ mm) {
    int i = threadIdx.x;
    if (i < 2 * B_) mm[i] = (i & 1) ? 0u : 0xFFFFFFFFu;  // even: min, odd: max
}

// grid = (WH/1024, B), block = 1024.
// tid = dq*256 + whl : d-quarter dq in [0,4), wh-lane whl in [0,256).
// Each thread: 4 wh (float4) x 64 d. Partials combined via LDS.
__global__ __launch_bounds__(1024) void score_kernel(
    const float* __restrict__ q, const float* __restrict__ value,
    float* __restrict__ score, float* __restrict__ invn,
    unsigned int* __restrict__ mm)
{
    const int b   = blockIdx.y;
    const int tid = threadIdx.x;
    const int whl = tid & 255;
    const int dq  = tid >> 8;          // wave-uniform (64-lane waves)

    __shared__ float qs[D_];
    __shared__ float red[256];
    __shared__ float part[3 * 256 * 9];   // [dq-1][whl][8 vals], pad 9 vs banks

    // ---- q-row normalization (group dq==0 does it; all threads sync) ----
    float qv = 0.f;
    if (dq == 0) { qv = q[b * D_ + whl]; red[whl] = qv * qv; }
    __syncthreads();
    for (int s = 128; s > 0; s >>= 1) {
        if (dq == 0 && whl < s) red[whl] += red[whl + s];
        __syncthreads();
    }
    if (dq == 0) qs[whl] = qv * (1.0f / fmaxf(sqrtf(red[0]), 1e-12f));
    __syncthreads();

    // ---- partial reduction over this thread's 64-d quarter ----
    const int wh0 = (blockIdx.x * 256 + whl) * 4;
    const float* vb = value + ((size_t)b * D_ + (size_t)dq * 64) * WH_ + wh0;
    float ss0 = 0.f, ss1 = 0.f, ss2 = 0.f, ss3 = 0.f;
    float dt0 = 0.f, dt1 = 0.f, dt2 = 0.f, dt3 = 0.f;
#pragma unroll 16
    for (int d = 0; d < 64; ++d) {
        float4 v4 = *(const float4*)(vb + (size_t)d * WH_);
        float qd = qs[dq * 64 + d];
        ss0 += v4.x * v4.x; ss1 += v4.y * v4.y;
        ss2 += v4.z * v4.z; ss3 += v4.w * v4.w;
        dt0 += qd * v4.x;   dt1 += qd * v4.y;
        dt2 += qd * v4.z;   dt3 += qd * v4.w;
    }

    // ---- combine 4 partials via LDS ----
    if (dq > 0) {
        float* p = &part[((dq - 1) * 256 + whl) * 9];
        p[0] = ss0; p[1] = ss1; p[2] = ss2; p[3] = ss3;
        p[4] = dt0; p[5] = dt1; p[6] = dt2; p[7] = dt3;
    }
    __syncthreads();

    float mn = 0.f, mx = 0.f;
    if (dq == 0) {
#pragma unroll
        for (int c = 0; c < 3; ++c) {
            const float* p = &part[(c * 256 + whl) * 9];
            ss0 += p[0]; ss1 += p[1]; ss2 += p[2]; ss3 += p[3];
            dt0 += p[4]; dt1 += p[5]; dt2 += p[6]; dt3 += p[7];
        }
        float n0 = 1.0f / fmaxf(sqrtf(ss0), 1e-12f);
        float n1 = 1.0f / fmaxf(sqrtf(ss1), 1e-12f);
        float n2 = 1.0f / fmaxf(sqrtf(ss2), 1e-12f);
        float n3 = 1.0f / fmaxf(sqrtf(ss3), 1e-12f);
        float s0 = dt0 * n0, s1 = dt1 * n1, s2 = dt2 * n2, s3 = dt3 * n3;

        *(float4*)(score + (size_t)b * WH_ + wh0) = make_float4(s0, s1, s2, s3);
        *(float4*)(invn  + (size_t)b * WH_ + wh0) = make_float4(n0, n1, n2, n3);

        mn = fminf(fminf(s0, s1), fminf(s2, s3));
        mx = fmaxf(fmaxf(s0, s1), fmaxf(s2, s3));
    }

    // ---- block min/max (256 dq0 lanes) -> one atomic pair per block ----
    if (dq == 0) red[whl] = mn;
    __syncthreads();
    for (int s = 128; s > 0; s >>= 1) {
        if (dq == 0 && whl < s) red[whl] = fminf(red[whl], red[whl + s]);
        __syncthreads();
    }
    float bmn = red[0];
    __syncthreads();
    if (dq == 0) red[whl] = mx;
    __syncthreads();
    for (int s = 128; s > 0; s >>= 1) {
        if (dq == 0 && whl < s) red[whl] = fmaxf(red[whl], red[whl + s]);
        __syncthreads();
    }
    if (tid == 0) {
        atomicMin(&mm[2 * b],     fmap(bmn));
        atomicMax(&mm[2 * b + 1], fmap(red[0]));
    }
}

// Mirrored elementwise pass. grid = (4 * WH/1024, B), block = 256.
// dq reversed vs launch order so first-launched blocks read the most-recently
// cached (high-d) value lines; within a block d descends. nt stores keep the
// 269 MB output stream from evicting value from L2/L3.
__global__ __launch_bounds__(256) void ctx_kernel(
    const float* __restrict__ value, const float* __restrict__ score,
    const float* __restrict__ invn, const unsigned int* __restrict__ mm,
    float* __restrict__ out_ctx, float* __restrict__ out_attn)
{
    const int x  = blockIdx.x & (WH_ / 1024 - 1);
    const int dq = 3 - (blockIdx.x >> 4);           // 3,2,1,0 over launch order
    const int b  = blockIdx.y;
    const int wh0 = (x * 256 + threadIdx.x) * 4;

    const float mn = funmap(mm[2 * b]);
    const float sc = 1.0f / (funmap(mm[2 * b + 1]) - mn + 1e-8f);

    float4 s4 = *(const float4*)(score + (size_t)b * WH_ + wh0);
    float4 n4 = *(const float4*)(invn  + (size_t)b * WH_ + wh0);
    float4 a4;
    a4.x = (s4.x - mn) * sc; a4.y = (s4.y - mn) * sc;
    a4.z = (s4.z - mn) * sc; a4.w = (s4.w - mn) * sc;
    if (dq == 0) nt_store4(out_attn + (size_t)b * WH_ + wh0, a4);

    const float an0 = a4.x * n4.x, an1 = a4.y * n4.y;
    const float an2 = a4.z * n4.z, an3 = a4.w * n4.w;

    const float* vb = value   + (size_t)b * D_ * WH_ + wh0;
    float*       cb = out_ctx + (size_t)b * D_ * WH_ + wh0;
#pragma unroll 16
    for (int d = dq * 64 + 63; d >= dq * 64; --d) {
        float4 v4 = *(const float4*)(vb + (size_t)d * WH_);
        float4 c4;
        c4.x = an0 * v4.x; c4.y = an1 * v4.y;
        c4.z = an2 * v4.z; c4.w = an3 * v4.w;
        nt_store4(cb + (size_t)d * WH_, c4);
    }
}

extern "C" void kernel_launch(void* const* d_in, const int* in_sizes, int n_in,
                              void* d_out, int out_size, void* d_ws, size_t ws_size,
                              hipStream_t stream) {
    const float* q     = (const float*)d_in[0];   // [16,256]
    const float* value = (const float*)d_in[1];   // [16,256,128,128]

    float* out_ctx  = (float*)d_out;                       // B*D*WH floats
    float* out_attn = out_ctx + (size_t)B_ * D_ * WH_;     // B*WH floats

    // workspace: score [B*WH] f32 | invn [B*WH] f32 | mm [2*B] u32  (~2.1 MB)
    float* score = (float*)d_ws;
    float* invn  = score + (size_t)B_ * WH_;
    unsigned int* mm = (unsigned int*)(invn + (size_t)B_ * WH_);

    hipLaunchKernelGGL(init_mm_kernel, dim3(1), dim3(64), 0, stream, mm);
    hipLaunchKernelGGL(score_kernel, dim3(WH_ / 1024, B_), dim3(1024), 0, stream,
                       q, value, score, invn, mm);
    hipLaunchKernelGGL(ctx_kernel, dim3(4 * (WH_ / 1024), B_), dim3(256),
                       0, stream, value, score, invn, mm, out_ctx, out_attn);
}

// Round 5
// 142.734 us; speedup vs baseline: 1.0424x; 1.0424x over previous
//
#include <hip/hip_runtime.h>
#include <hip/hip_bf16.h>

// Problem: CrossViewFusionModule
//   global_query: [B=16, D=256] f32
//   value:        [B=16, D=256, W=128, H=128] f32
//   q = l2norm(q, axis=-1); v = l2norm(value, axis=D)
//   score[b,wh] = sum_d q[b,d]*v[b,d,wh]
//   attn = (score - min_b) / (max_b - min_b + 1e-8)   (min/max over wh per b)
//   context = attn * v
//   outputs: (context [B,D,W,H], attn [B,1,W,H]) concatenated in d_out.
//
// R5: ctx reverted EXACTLY to R3 (136.1 us version: nt stores + L3 mirror).
// score keeps R3's 256-block/256-thread shape; only change is an explicit
// 8-deep register double-buffer pipeline (issue next 8 loads before consuming
// current 8) -> ~8 KB in flight per wave instead of ~1 KB. Theory: R3 score
// was load-latency-serialized (3.2 TB/s ~= 1 load in flight per wave).

#define B_  16
#define D_  256
#define WH_ 16384   // 128*128

// ---- monotone float <-> sortable uint mapping (for exact atomic min/max) ----
__device__ __forceinline__ unsigned int fmap(float f) {
    unsigned int u = __float_as_uint(f);
    return (u & 0x80000000u) ? ~u : (u | 0x80000000u);
}
__device__ __forceinline__ float funmap(unsigned int u) {
    unsigned int b = (u & 0x80000000u) ? (u ^ 0x80000000u) : ~u;
    return __uint_as_float(b);
}

typedef float f32x4_t __attribute__((ext_vector_type(4)));
__device__ __forceinline__ void nt_store4(float* p, float4 v) {
    f32x4_t w = {v.x, v.y, v.z, v.w};
    __builtin_nontemporal_store(w, (f32x4_t*)p);   // global_store_dwordx4 ... nt
}

__global__ void init_mm_kernel(unsigned int* __restrict__ mm) {
    int i = threadIdx.x;
    if (i < 2 * B_) mm[i] = (i & 1) ? 0u : 0xFFFFFFFFu;  // even: min, odd: max
}

// One block = 1024 contiguous wh positions of one b (256 threads x float4).
// grid = (WH/1024, B). d ascends 0..255 (defines the L3 recency order).
__global__ __launch_bounds__(256) void score_kernel(
    const float* __restrict__ q, const float* __restrict__ value,
    float* __restrict__ score, float* __restrict__ invn,
    unsigned int* __restrict__ mm)
{
    const int b   = blockIdx.y;
    const int tid = threadIdx.x;
    __shared__ float qs[D_];
    __shared__ float red[256];

    // ---- normalize q row in LDS ----
    float qv = q[b * D_ + tid];
    red[tid] = qv * qv;
    __syncthreads();
    for (int s = 128; s > 0; s >>= 1) {
        if (tid < s) red[tid] += red[tid + s];
        __syncthreads();
    }
    float qnorm2 = red[0];
    __syncthreads();
    qs[tid] = qv * (1.0f / fmaxf(sqrtf(qnorm2), 1e-12f));
    __syncthreads();

    // ---- per-thread: 4 wh columns, reduce over D, 8-deep load pipeline ----
    const int wh0 = (blockIdx.x * 256 + tid) * 4;
    const float* vb = value + (size_t)b * D_ * WH_ + wh0;
    float ss0 = 0.f, ss1 = 0.f, ss2 = 0.f, ss3 = 0.f;
    float dt0 = 0.f, dt1 = 0.f, dt2 = 0.f, dt3 = 0.f;

#define LDV(k) (*(const float4*)(vb + (size_t)(k) * WH_))
#define ACC(v4, qd) { float qq = (qd);                                        \
    ss0 += v4.x * v4.x; ss1 += v4.y * v4.y;                                   \
    ss2 += v4.z * v4.z; ss3 += v4.w * v4.w;                                   \
    dt0 += qq * v4.x;   dt1 += qq * v4.y;                                     \
    dt2 += qq * v4.z;   dt3 += qq * v4.w; }

    float4 a0 = LDV(0), a1 = LDV(1), a2 = LDV(2), a3 = LDV(3);
    float4 a4 = LDV(4), a5 = LDV(5), a6 = LDV(6), a7 = LDV(7);
#pragma unroll
    for (int d = 0; d < D_; d += 16) {
        // issue next 8 loads (B-phase) before consuming A-phase
        float4 b0 = LDV(d + 8),  b1 = LDV(d + 9),  b2 = LDV(d + 10), b3 = LDV(d + 11);
        float4 b4 = LDV(d + 12), b5 = LDV(d + 13), b6 = LDV(d + 14), b7 = LDV(d + 15);
        ACC(a0, qs[d + 0]); ACC(a1, qs[d + 1]); ACC(a2, qs[d + 2]); ACC(a3, qs[d + 3]);
        ACC(a4, qs[d + 4]); ACC(a5, qs[d + 5]); ACC(a6, qs[d + 6]); ACC(a7, qs[d + 7]);
        if (d + 16 < D_) {   // issue the following A-phase loads
            a0 = LDV(d + 16); a1 = LDV(d + 17); a2 = LDV(d + 18); a3 = LDV(d + 19);
            a4 = LDV(d + 20); a5 = LDV(d + 21); a6 = LDV(d + 22); a7 = LDV(d + 23);
        }
        ACC(b0, qs[d + 8]);  ACC(b1, qs[d + 9]);  ACC(b2, qs[d + 10]); ACC(b3, qs[d + 11]);
        ACC(b4, qs[d + 12]); ACC(b5, qs[d + 13]); ACC(b6, qs[d + 14]); ACC(b7, qs[d + 15]);
    }
#undef LDV
#undef ACC

    float n0 = 1.0f / fmaxf(sqrtf(ss0), 1e-12f);
    float n1 = 1.0f / fmaxf(sqrtf(ss1), 1e-12f);
    float n2 = 1.0f / fmaxf(sqrtf(ss2), 1e-12f);
    float n3 = 1.0f / fmaxf(sqrtf(ss3), 1e-12f);
    float s0 = dt0 * n0, s1 = dt1 * n1, s2 = dt2 * n2, s3 = dt3 * n3;

    *(float4*)(score + (size_t)b * WH_ + wh0) = make_float4(s0, s1, s2, s3);
    *(float4*)(invn  + (size_t)b * WH_ + wh0) = make_float4(n0, n1, n2, n3);

    // ---- block min/max -> one atomic pair per block ----
    float mn = fminf(fminf(s0, s1), fminf(s2, s3));
    float mx = fmaxf(fmaxf(s0, s1), fmaxf(s2, s3));
    red[tid] = mn;
    __syncthreads();
    for (int s = 128; s > 0; s >>= 1) {
        if (tid < s) red[tid] = fminf(red[tid], red[tid + s]);
        __syncthreads();
    }
    float bmn = red[0];
    __syncthreads();
    red[tid] = mx;
    __syncthreads();
    for (int s = 128; s > 0; s >>= 1) {
        if (tid < s) red[tid] = fmaxf(red[tid], red[tid + s]);
        __syncthreads();
    }
    if (tid == 0) {
        atomicMin(&mm[2 * b],     fmap(bmn));
        atomicMax(&mm[2 * b + 1], fmap(red[0]));
    }
}

// Mirrored elementwise pass (EXACT R3 form). grid = (4 * WH/1024, B), block 256.
// blockIdx.x = (dq << 4) | x ; d-quarter dq walked DESCENDING within block.
// ctx/attn written with non-temporal stores (don't evict value from caches).
__global__ __launch_bounds__(256) void ctx_kernel(
    const float* __restrict__ value, const float* __restrict__ score,
    const float* __restrict__ invn, const unsigned int* __restrict__ mm,
    float* __restrict__ out_ctx, float* __restrict__ out_attn)
{
    const int x  = blockIdx.x & (WH_ / 1024 - 1);
    const int dq = blockIdx.x >> 4;                 // 0..3
    const int b  = blockIdx.y;
    const int wh0 = (x * 256 + threadIdx.x) * 4;

    const float mn = funmap(mm[2 * b]);
    const float sc = 1.0f / (funmap(mm[2 * b + 1]) - mn + 1e-8f);

    float4 s4 = *(const float4*)(score + (size_t)b * WH_ + wh0);
    float4 n4 = *(const float4*)(invn  + (size_t)b * WH_ + wh0);
    float4 a4;
    a4.x = (s4.x - mn) * sc; a4.y = (s4.y - mn) * sc;
    a4.z = (s4.z - mn) * sc; a4.w = (s4.w - mn) * sc;
    if (dq == 0) nt_store4(out_attn + (size_t)b * WH_ + wh0, a4);

    const float an0 = a4.x * n4.x, an1 = a4.y * n4.y;
    const float an2 = a4.z * n4.z, an3 = a4.w * n4.w;

    const float* vb = value   + (size_t)b * D_ * WH_ + wh0;
    float*       cb = out_ctx + (size_t)b * D_ * WH_ + wh0;
#pragma unroll 4
    for (int d = dq * 64 + 63; d >= dq * 64; --d) {
        float4 v4 = *(const float4*)(vb + (size_t)d * WH_);
        float4 c4;
        c4.x = an0 * v4.x; c4.y = an1 * v4.y;
        c4.z = an2 * v4.z; c4.w = an3 * v4.w;
        nt_store4(cb + (size_t)d * WH_, c4);
    }
}

extern "C" void kernel_launch(void* const* d_in, const int* in_sizes, int n_in,
                              void* d_out, int out_size, void* d_ws, size_t ws_size,
                              hipStream_t stream) {
    const float* q     = (const float*)d_in[0];   // [16,256]
    const float* value = (const float*)d_in[1];   // [16,256,128,128]

    float* out_ctx  = (float*)d_out;                       // B*D*WH floats
    float* out_attn = out_ctx + (size_t)B_ * D_ * WH_;     // B*WH floats

    // workspace: score [B*WH] f32 | invn [B*WH] f32 | mm [2*B] u32  (~2.1 MB)
    float* score = (float*)d_ws;
    float* invn  = score + (size_t)B_ * WH_;
    unsigned int* mm = (unsigned int*)(invn + (size_t)B_ * WH_);

    hipLaunchKernelGGL(init_mm_kernel, dim3(1), dim3(64), 0, stream, mm);
    hipLaunchKernelGGL(score_kernel, dim3(WH_ / 1024, B_), dim3(256), 0, stream,
                       q, value, score, invn, mm);
    hipLaunchKernelGGL(ctx_kernel, dim3(4 * (WH_ / 1024), B_), dim3(256),
                       0, stream, value, score, invn, mm, out_ctx, out_attn);
}